// Round 6
// baseline (112.010 us; speedup 1.0000x reference)
//
#include <hip/hip_runtime.h>
#include <math.h>

// Problem constants
#define NB    256           // N nodes
#define EDIM  16            // edge MLP hidden
#define FINN  32            // Fin
#define FOUTN 32            // Fout
#define BT    128           // B*T
#define KKD   4096          // GEMM K index: e*256 + j

typedef __attribute__((ext_vector_type(8))) short short8;   // 8 bf16 = 4 VGPRs
typedef __attribute__((ext_vector_type(4))) float floatx4;  // MFMA accumulator

#define MFMA16(a,b,c) __builtin_amdgcn_mfma_f32_16x16x32_bf16((a),(b),(c),0,0,0)

__device__ __forceinline__ float gelu_f(float v) {
    return 0.5f * v * (1.0f + erff(v * 0.70710678118654752f));
}
__device__ __forceinline__ ushort f2bf(float x) {
    union { float f; unsigned u; } v; v.f = x;
    unsigned r = (v.u + 0x7FFFu + ((v.u >> 16) & 1u)) >> 16;
    return (ushort)r;
}
__device__ __forceinline__ float bf2f(ushort b) {
    union { unsigned u; float f; } v; v.u = ((unsigned)b) << 16; return v.f;
}

// ---------------------------------------------------------------------------
// Stage 1: H[i][e*256 + j] = bf16(gelu(adj[i,j]*w1[e] + b1[e]))   (2 MiB)
// ---------------------------------------------------------------------------
__global__ __launch_bounds__(256) void h_kernel(const float* __restrict__ adj,
                                                const float* __restrict__ w1,
                                                const float* __restrict__ b1,
                                                ushort* __restrict__ H) {
    int i   = blockIdx.x;
    int tid = threadIdx.x;
    int e   = tid >> 4;
    int seg = tid & 15;
    float w = w1[e], b = b1[e];
    const float4* arow = (const float4*)(adj + (size_t)i * NB + seg * 16);
    ushort tmp[16];
    #pragma unroll
    for (int q = 0; q < 4; ++q) {
        float4 a = arow[q];
        tmp[q*4+0] = f2bf(gelu_f(a.x * w + b));
        tmp[q*4+1] = f2bf(gelu_f(a.y * w + b));
        tmp[q*4+2] = f2bf(gelu_f(a.z * w + b));
        tmp[q*4+3] = f2bf(gelu_f(a.w * w + b));
    }
    int4* dst = (int4*)(H + (size_t)i * KKD + e * 256 + seg * 16);
    dst[0] = *(int4*)&tmp[0];
    dst[1] = *(int4*)&tmp[8];
}

// ---------------------------------------------------------------------------
// Fused y2 + GEMM + epilogue. Block = (bt, iq); 256 threads = 4 waves;
// grid 512 blocks, LDS ~58 KB -> 2 blocks/CU = 8 waves/CU (2/SIMD).
//   Chunk c = edge-feature e=c (256 k). Per chunk:
//     produce: wave w computes y2 tiles jt in [4w,4w+4) x both o-halves
//              (8 MFMA) from LDS bf16 x + register w2 frags; D-layout lands
//              as 4-consecutive-j runs -> uint2 LDS store into Bs.
//     gemm:    wave's 16 i-rows: A-frags straight from global H (L2-hot),
//              B from Bs chunk; 8 k-steps x 2 MFMA.
//   Double-buffered Bs, one barrier per chunk; barrier drains overlap with
//   the co-resident block (m114).
//   Epilogue: acc += x@node_w (1 MFMA/tile) + bias2; gelu; store.
// ---------------------------------------------------------------------------
#define CH   256   // k per chunk (one e)
#define NCH  16
#define BSP  264   // Bs padded row (bf16): 528 B, 16B-aligned
#define XBP  40    // xb/nwT padded row (bf16): 80 B, 16B-aligned

__global__ __launch_bounds__(256, 2) void fused_kernel(
        const float* __restrict__ x,      const float* __restrict__ w2,
        const float* __restrict__ b2,     const float* __restrict__ node_w,
        const float* __restrict__ node_b, const ushort* __restrict__ H,
        float* __restrict__ out) {
    __shared__ ushort xb[NB][XBP];      // 20 KiB   x[bt] in bf16
    __shared__ ushort Bs[2][32][BSP];   // 33 KiB   y2 chunk dbuf [o][j]
    __shared__ ushort nwT[32][XBP];     // 2.5 KiB  node_w^T in bf16
    __shared__ float  Sp[8][32];
    __shared__ float  Sv[32];
    __shared__ float  bias2[32];

    int bt   = blockIdx.x;              // 0..127
    int iq   = blockIdx.y;              // 0..3 -> i rows [iq*64, +64)
    int tid  = threadIdx.x;
    int wv   = tid >> 6;                // 0..3
    int lane = tid & 63;
    int m    = lane & 15;
    int quad = lane >> 4;

    // ---- fill xb (bf16) + nwT ----
    const float4* xg = (const float4*)(x + (size_t)bt * NB * FINN);
    #pragma unroll
    for (int it = 0; it < 8; ++it) {
        int idx4 = it * 256 + tid;      // 2048 float4s total
        float4 v = xg[idx4];
        int j = idx4 >> 3, f = (idx4 & 7) * 4;
        unsigned lo = (unsigned)f2bf(v.x) | ((unsigned)f2bf(v.y) << 16);
        unsigned hi = (unsigned)f2bf(v.z) | ((unsigned)f2bf(v.w) << 16);
        uint2 p; p.x = lo; p.y = hi;
        *(uint2*)&xb[j][f] = p;
    }
    {
        float4 v = ((const float4*)node_w)[tid];   // node_w[f][o], f=tid>>3
        int f = tid >> 3, o = (tid & 7) * 4;
        nwT[o + 0][f] = f2bf(v.x); nwT[o + 1][f] = f2bf(v.y);
        nwT[o + 2][f] = f2bf(v.z); nwT[o + 3][f] = f2bf(v.w);
    }
    __syncthreads();

    // ---- S partials (per-f column sums of x[bt]) ----
    {
        int f = tid & 31, grp = tid >> 5;
        float s = 0.f;
        for (int j = grp * 32; j < grp * 32 + 32; ++j) s += bf2f(xb[j][f]);
        Sp[grp][f] = s;
    }

    // ---- production A-frags: wave's 4 j-tiles (rows wv*64 .. wv*64+64) ----
    short8 afr[4];
    #pragma unroll
    for (int t = 0; t < 4; ++t)
        afr[t] = *(short8*)&xb[(wv * 4 + t) * 16 + m][quad * 8];

    __syncthreads();                    // Sp complete
    if (tid < 32) {
        float s = 0.f;
        #pragma unroll
        for (int g = 0; g < 8; ++g) s += Sp[g][tid];
        Sv[tid] = s;
    }

    floatx4 acc[2] = {};                // 16 i-rows x 2 o-tiles
    int i0g = iq * 64 + wv * 16;        // wave's M rows in H / out

    // w2 fragment loader for edge e: both o-halves
    #define WLOAD(e, d0, d1)                                                  \
    {                                                                         \
        const float* wp = w2 + (size_t)(e) * (FINN * FOUTN)                   \
                          + (quad * 8) * FOUTN + m;                           \
        _Pragma("unroll")                                                     \
        for (int i = 0; i < 8; ++i) {                                         \
            d0[i] = (short)f2bf(wp[i * FOUTN]);                               \
            d1[i] = (short)f2bf(wp[i * FOUTN + 16]);                          \
        }                                                                     \
    }

    // produce chunk e into Bs[buf]
    #define PRODUCE(buf, wa, wb)                                              \
    {                                                                         \
        _Pragma("unroll")                                                     \
        for (int t = 0; t < 4; ++t) {                                         \
            floatx4 z = {0.f, 0.f, 0.f, 0.f};                                 \
            floatx4 d0 = MFMA16(afr[t], wa, z);                               \
            floatx4 d1 = MFMA16(afr[t], wb, z);                               \
            int col = (wv * 4 + t) * 16 + quad * 4;                           \
            uint2 p0, p1;                                                     \
            p0.x = (unsigned)f2bf(d0[0]) | ((unsigned)f2bf(d0[1]) << 16);     \
            p0.y = (unsigned)f2bf(d0[2]) | ((unsigned)f2bf(d0[3]) << 16);     \
            p1.x = (unsigned)f2bf(d1[0]) | ((unsigned)f2bf(d1[1]) << 16);     \
            p1.y = (unsigned)f2bf(d1[2]) | ((unsigned)f2bf(d1[3]) << 16);     \
            *(uint2*)&Bs[buf][     m][col] = p0;                              \
            *(uint2*)&Bs[buf][16 + m][col] = p1;                              \
        }                                                                     \
    }

    short8 wc0, wc1;                    // current chunk's w2 frags
    WLOAD(0, wc0, wc1);
    PRODUCE(0, wc0, wc1);
    __syncthreads();
    if (tid < 32) {                     // bias2 (read only in epilogue)
        float bb = node_b[tid];
        #pragma unroll
        for (int f = 0; f < FINN; ++f) bb += Sv[f] * b2[f * FOUTN + tid];
        bias2[tid] = bb;
    }

    #pragma unroll
    for (int c = 0; c < NCH; ++c) {
        if (c < NCH - 1) {
            short8 wn0, wn1;
            WLOAD(c + 1, wn0, wn1);
            PRODUCE((c + 1) & 1, wn0, wn1);
        }
        // gemm on chunk c from Bs[c&1]
        const ushort* Hrow0 = H + (size_t)(i0g + m) * KKD + c * CH;
        #pragma unroll
        for (int kk = 0; kk < CH; kk += 32) {
            short8 a0 = *(const short8*)(Hrow0 + kk + quad * 8);
            short8 b0 = *(short8*)&Bs[c & 1][     m][kk + quad * 8];
            short8 b1 = *(short8*)&Bs[c & 1][16 + m][kk + quad * 8];
            acc[0] = MFMA16(a0, b0, acc[0]);
            acc[1] = MFMA16(a0, b1, acc[1]);
        }
        __syncthreads();
    }

    // ---- epilogue: + x@node_w (one MFMA per tile), + bias2, gelu, store ----
    {
        short8 xa = *(short8*)&xb[i0g + m][quad * 8];
        #pragma unroll
        for (int tn = 0; tn < 2; ++tn) {
            short8 nb = *(short8*)&nwT[tn * 16 + m][quad * 8];
            acc[tn] = MFMA16(xa, nb, acc[tn]);
        }
    }
    #pragma unroll
    for (int tn = 0; tn < 2; ++tn) {
        int o = tn * 16 + m;
        float bz = bias2[o];
        #pragma unroll
        for (int r = 0; r < 4; ++r) {
            int row = i0g + quad * 4 + r;
            out[((size_t)bt * NB + row) * FOUTN + o] = gelu_f(acc[tn][r] + bz);
        }
    }
}

// ---------------------------------------------------------------------------
extern "C" void kernel_launch(void* const* d_in, const int* in_sizes, int n_in,
                              void* d_out, int out_size, void* d_ws, size_t ws_size,
                              hipStream_t stream) {
    const float* x      = (const float*)d_in[0];
    const float* adj    = (const float*)d_in[1];
    const float* w1     = (const float*)d_in[2];
    const float* b1     = (const float*)d_in[3];
    const float* w2     = (const float*)d_in[4];
    const float* b2     = (const float*)d_in[5];
    const float* node_w = (const float*)d_in[6];
    const float* node_b = (const float*)d_in[7];
    float* out = (float*)d_out;

    ushort* H = (ushort*)d_ws;          // 256*4096 bf16 = 2 MiB (only ws use)

    hipLaunchKernelGGL(h_kernel, dim3(NB), dim3(256), 0, stream,
                       adj, w1, b1, H);
    hipLaunchKernelGGL(fused_kernel, dim3(BT, 4), dim3(256), 0, stream,
                       x, w2, b2, node_w, node_b, H, out);
}